// Round 5
// baseline (373.308 us; speedup 1.0000x reference)
//
#include <hip/hip_runtime.h>
#include <stdint.h>

// MultiHeadAttention  B=8, S=2048, D=768  (fp32 in/out; bf16 MFMA compute)
//
// Pipeline:
//   convert : all 9 fp32 inputs -> bf16 in ws
//   qkv_k   : fused Q/K/V projections (grid 128x18); V stored transposed Vt[b][e][s]
//   score_k : E = exp(min(Q.K^T/sqrt(D),30)) bf16 + fused rowsum atomicAdd -> rl (raw sums)
//   pv_k    : attn = (E @ V) * rcp(rl)
//   out_k   : out = attn@Wp^T + bp  (fp32)
//
// GEMM core: 128x128 tile, BK=64 (two 32-k LDS chunks), global_load_lds width=16,
// *** 32x32x16 bf16 MFMA *** (8 MFMA/chunk/wave vs 16 with 16x16x32: -17% matrix-pipe
// cycles, half the issue slots). Layouts: A/B frag m=lane&31, k=(lane>>5)*8+j;
// C/D col=lane&31, row=(reg&3)+8*(reg>>2)+4*(lane>>5)  [HW-verified m74/m101].
// All epilogues stage C through LDS and store 16B-vectorized.

typedef __attribute__((ext_vector_type(8))) short short8;
typedef __attribute__((ext_vector_type(16))) float f32x16;

typedef const __attribute__((address_space(1))) void gvoid_t;
typedef __attribute__((address_space(3))) void lvoid_t;

__device__ __forceinline__ float b2f(unsigned short u) {
  union { unsigned int u; float f; } v;
  v.u = ((unsigned int)u) << 16;
  return v.f;
}
__device__ __forceinline__ unsigned short f2b(float f) {
  union { float f; unsigned int u; } v; v.f = f;
  unsigned int u = v.u;
  return (unsigned short)((u + 0x7fffu + ((u >> 16) & 1u)) >> 16);
}

// ---------------- fp32 -> bf16 conversion ----------------
struct Cvt9 {
  const void* s[9];
  unsigned short* d[9];
  long long n8[9];
  long long total8;
};

__global__ __launch_bounds__(256) void convert_inputs(Cvt9 C) {
  long long g = (long long)blockIdx.x * 256 + threadIdx.x;
  if (g >= C.total8) return;
  int s = 0;
  long long off = g;
  while (off >= C.n8[s]) { off -= C.n8[s]; ++s; }
  const float* sf = (const float*)C.s[s] + off * 8;
  unsigned short* dp = C.d[s] + off * 8;
  float4 a = ((const float4*)sf)[0];
  float4 b = ((const float4*)sf)[1];
  uint4 o;
  o.x = (unsigned int)f2b(a.x) | ((unsigned int)f2b(a.y) << 16);
  o.y = (unsigned int)f2b(a.z) | ((unsigned int)f2b(a.w) << 16);
  o.z = (unsigned int)f2b(b.x) | ((unsigned int)f2b(b.y) << 16);
  o.w = (unsigned int)f2b(b.z) | ((unsigned int)f2b(b.w) << 16);
  *(uint4*)dp = o;
}

// ---------------- GEMM core (NT, BK=64, 32x32x16): acc += A[m0..][k] B[n0..][k]^T --
// LDS per matrix: [2 chunks][128 rows][32 k]
__device__ __forceinline__ void gemm_core(
    const unsigned short* __restrict__ Ab, const unsigned short* __restrict__ Bb,
    int lda, int ldb, int K, int m0, int n0,
    unsigned short* As, unsigned short* Bs, f32x16 (&acc)[2][2])
{
  const int t    = threadIdx.x;
  const int w    = t >> 6;
  const int lane = t & 63;
  const int l32  = lane & 31;
  const int kh8  = (lane >> 5) * 8;
  const int wr   = w >> 1;
  const int wc   = w & 1;
  const int srow  = t >> 2;
  const int skoff = (t & 3) * 8;

  for (int k0 = 0; k0 < K; k0 += 64) {
#pragma unroll
    for (int c = 0; c < 2; ++c) {
#pragma unroll
      for (int r = 0; r < 2; ++r) {
        const unsigned short* ga = Ab + (size_t)(m0 + r * 64 + srow) * lda + (k0 + c * 32 + skoff);
        __builtin_amdgcn_global_load_lds((gvoid_t*)ga, (lvoid_t*)(As + c * 4096 + r * 2048 + w * 512), 16, 0, 0);
        const unsigned short* gb = Bb + (size_t)(n0 + r * 64 + srow) * ldb + (k0 + c * 32 + skoff);
        __builtin_amdgcn_global_load_lds((gvoid_t*)gb, (lvoid_t*)(Bs + c * 4096 + r * 2048 + w * 512), 16, 0, 0);
      }
    }
    __syncthreads();

#pragma unroll
    for (int c = 0; c < 2; ++c) {
#pragma unroll
      for (int h = 0; h < 2; ++h) {     // k-half of 16 within the 32-k chunk
        short8 af[2], bf[2];
#pragma unroll
        for (int i = 0; i < 2; ++i)
          af[i] = *(const short8*)(As + c * 4096 + (wr * 64 + i * 32 + l32) * 32 + h * 16 + kh8);
#pragma unroll
        for (int j = 0; j < 2; ++j)
          bf[j] = *(const short8*)(Bs + c * 4096 + (wc * 64 + j * 32 + l32) * 32 + h * 16 + kh8);

#pragma unroll
        for (int i = 0; i < 2; ++i)
#pragma unroll
          for (int j = 0; j < 2; ++j)
            acc[i][j] = __builtin_amdgcn_mfma_f32_32x32x16_bf16(af[i], bf[j], acc[i][j], 0, 0, 0);
      }
    }
    __syncthreads();
  }
}

// ---------------- epilogue helpers ----------------
// mode 0: v += bias[ct] ; mode 2: v = exp(min(v*scale,30)) ; mode 3: v *= rcp(rl[row])
__device__ __forceinline__ void tile_to_lds(
    unsigned short* Ls, f32x16 (&acc)[2][2], int mode,
    const unsigned short* bias_n0, const float* rlrow, float scale)
{
  const int t = threadIdx.x;
  const int w = t >> 6, lane = t & 63;
  const int l32 = lane & 31, wr = w >> 1, wc = w & 1;
  const int r4 = (lane >> 5) * 4;
#pragma unroll
  for (int j = 0; j < 2; ++j) {
    const int ct = wc * 64 + j * 32 + l32;
    const float bv = (mode == 0) ? b2f(bias_n0[ct]) : 0.f;
#pragma unroll
    for (int i = 0; i < 2; ++i) {
#pragma unroll
      for (int g = 0; g < 4; ++g) {
        const int rbase = wr * 64 + i * 32 + g * 8 + r4;
#pragma unroll
        for (int r = 0; r < 4; ++r) {
          float v = acc[i][j][g * 4 + r];
          if (mode == 0)      v += bv;
          else if (mode == 2) v = __expf(fminf(v * scale, 30.f));
          else                v *= __builtin_amdgcn_rcpf(rlrow[rbase + r]);
          Ls[(rbase + r) * 136 + ct] = f2b(v);
        }
      }
    }
  }
  __syncthreads();
}

__device__ __forceinline__ void lds_to_global_bf16(
    const unsigned short* Ls, unsigned short* Cg, int ldc)
{
  const int t = threadIdx.x;
  const int cr = t >> 4, cc = (t & 15) * 8;
#pragma unroll
  for (int r0 = 0; r0 < 128; r0 += 16) {
    uint4 v = *(const uint4*)(Ls + (r0 + cr) * 136 + cc);
    *(uint4*)(Cg + (size_t)(r0 + cr) * ldc + cc) = v;
  }
}

// ---------------- qkv: fused projections ----------------
__global__ __launch_bounds__(256, 2) void qkv_k(
    const unsigned short* __restrict__ xb,
    const unsigned short* __restrict__ Wq, const unsigned short* __restrict__ bq,
    const unsigned short* __restrict__ Wk, const unsigned short* __restrict__ bk,
    const unsigned short* __restrict__ Wv, const unsigned short* __restrict__ bv,
    unsigned short* __restrict__ qb, unsigned short* __restrict__ kb,
    unsigned short* __restrict__ vt)
{
  __shared__ unsigned short smem[17408];
  const int sel = blockIdx.y / 6;
  const int n0  = (blockIdx.y % 6) * 128;
  const int m0  = blockIdx.x * 128;

  const unsigned short* W;
  const unsigned short* bi;
  if (sel == 0)      { W = Wq; bi = bq; }
  else if (sel == 1) { W = Wk; bi = bk; }
  else               { W = Wv; bi = bv; }

  f32x16 acc[2][2] = {};
  gemm_core(xb, W, 768, 768, 768, m0, n0, smem, smem + 8192, acc);

  const int t = threadIdx.x;
  const int w = t >> 6, lane = t & 63;
  const int l32 = lane & 31, wr = w >> 1, wc = w & 1;
  const int r4 = (lane >> 5) * 4;

  if (sel < 2) {
    tile_to_lds(smem, acc, 0, bi + n0, nullptr, 0.f);
    unsigned short* dst = (sel == 0) ? qb : kb;
    lds_to_global_bf16(smem, dst + (size_t)m0 * 768 + n0, 768);
    return;
  }

  // V: transpose epilogue into Vt[b][e][s]  (Ls as [col][row], stride 136)
  unsigned short* Ls = smem;
#pragma unroll
  for (int j = 0; j < 2; ++j) {
    const int ct = wc * 64 + j * 32 + l32;
    const float bvv = b2f(bi[n0 + ct]);
#pragma unroll
    for (int i = 0; i < 2; ++i) {
#pragma unroll
      for (int g = 0; g < 4; ++g) {
        const int rbase = wr * 64 + i * 32 + g * 8 + r4;
        ushort4 pk;
        pk.x = f2b(acc[i][j][g * 4 + 0] + bvv);
        pk.y = f2b(acc[i][j][g * 4 + 1] + bvv);
        pk.z = f2b(acc[i][j][g * 4 + 2] + bvv);
        pk.w = f2b(acc[i][j][g * 4 + 3] + bvv);
        *(ushort4*)(Ls + ct * 136 + rbase) = pk;
      }
    }
  }
  __syncthreads();
  const int bb  = m0 >> 11;
  const int sin = m0 & 2047;
  unsigned short* Cb = vt + (size_t)bb * (768 * 2048);
#pragma unroll
  for (int e0 = 0; e0 < 128; e0 += 16) {
    const int et = e0 + (t >> 4);
    const int st = (t & 15) * 8;
    uint4 val = *(const uint4*)(Ls + et * 136 + st);
    *(uint4*)(Cb + (size_t)(n0 + et) * 2048 + (sin + st)) = val;
  }
}

// ---------------- score: E = exp(QK^T/sqrt(D)) + fused rowsum ----------------
__global__ __launch_bounds__(256, 2) void score_k(
    const unsigned short* __restrict__ Q, const unsigned short* __restrict__ Kb,
    unsigned short* __restrict__ E, float* __restrict__ rl, float scale)
{
  __shared__ unsigned short smem[17408];
  const int m0 = blockIdx.x * 128, n0 = blockIdx.y * 128, bz = blockIdx.z;

  f32x16 acc[2][2] = {};
  gemm_core(Q + (size_t)bz * 1572864, Kb + (size_t)bz * 1572864,
            768, 768, 768, m0, n0, smem, smem + 8192, acc);

  tile_to_lds(smem, acc, 2, nullptr, nullptr, scale);
  lds_to_global_bf16(smem, E + (size_t)bz * 4194304 + (size_t)m0 * 2048 + n0, 2048);

  // fused partial rowsum from the staged LDS tile
  const int t = threadIdx.x;
  const int row = t >> 1, half = t & 1;
  const unsigned short* lr = smem + row * 136 + half * 64;
  float s = 0.f;
#pragma unroll
  for (int q8 = 0; q8 < 8; ++q8) {
    uint4 v = *(const uint4*)(lr + q8 * 8);
    unsigned int uu[4] = {v.x, v.y, v.z, v.w};
#pragma unroll
    for (int c = 0; c < 4; ++c)
      s += b2f((unsigned short)(uu[c] & 0xffffu)) + b2f((unsigned short)(uu[c] >> 16));
  }
  s += __shfl_xor(s, 1);
  if (half == 0) atomicAdd(rl + bz * 2048 + m0 + row, s);
}

// ---------------- pv: attn = (E @ V) * rcp(rowsum) ----------------
__global__ __launch_bounds__(256, 2) void pv_k(
    const unsigned short* __restrict__ E, const unsigned short* __restrict__ Vt,
    const float* __restrict__ rl, unsigned short* __restrict__ attn)
{
  __shared__ unsigned short smem[17408];
  const int m0 = blockIdx.x * 128, n0 = blockIdx.y * 128, bz = blockIdx.z;

  f32x16 acc[2][2] = {};
  gemm_core(E + (size_t)bz * 4194304, Vt + (size_t)bz * 1572864,
            2048, 2048, 2048, m0, n0, smem, smem + 8192, acc);

  tile_to_lds(smem, acc, 3, nullptr, rl + bz * 2048 + m0, 0.f);
  lds_to_global_bf16(smem, attn + (size_t)bz * 1572864 + (size_t)m0 * 768 + n0, 768);
}

// ---------------- out: final projection (fp32 output) ----------------
__global__ __launch_bounds__(256, 2) void out_k(
    const unsigned short* __restrict__ attn,
    const unsigned short* __restrict__ Wp, const unsigned short* __restrict__ bp,
    float* __restrict__ Of)
{
  __shared__ unsigned short smem[17408];
  const int m0 = blockIdx.x * 128, n0 = blockIdx.y * 128;

  f32x16 acc[2][2] = {};
  gemm_core(attn, Wp, 768, 768, 768, m0, n0, smem, smem + 8192, acc);

  // fp32 output: two half-tiles (cols 0-63 then 64-127) staged as float through LDS
  const int t = threadIdx.x;
  const int w = t >> 6, lane = t & 63;
  const int l32 = lane & 31, wr = w >> 1, wc = w & 1;
  const int r4 = (lane >> 5) * 4;
  float* Lf = (float*)smem;     // 128 x 68 floats = 34816 B
#pragma unroll
  for (int h = 0; h < 2; ++h) {
    __syncthreads();
    if (wc == h) {
#pragma unroll
      for (int j = 0; j < 2; ++j) {
        const int cl = j * 32 + l32;                // 0..63 within half
        const float bvv = b2f(bp[n0 + h * 64 + cl]);
#pragma unroll
        for (int i = 0; i < 2; ++i) {
#pragma unroll
          for (int g = 0; g < 4; ++g) {
            const int rbase = wr * 64 + i * 32 + g * 8 + r4;
#pragma unroll
            for (int r = 0; r < 4; ++r)
              Lf[(rbase + r) * 68 + cl] = acc[i][j][g * 4 + r] + bvv;
          }
        }
      }
    }
    __syncthreads();
    const int cr = t >> 4, cc = (t & 15) * 4;
#pragma unroll
    for (int r0 = 0; r0 < 128; r0 += 16) {
      float4 v = *(const float4*)(Lf + (r0 + cr) * 68 + cc);
      *(float4*)(Of + (size_t)(m0 + r0 + cr) * 768 + n0 + h * 64 + cc) = v;
    }
  }
}

extern "C" void kernel_launch(void* const* d_in, const int* in_sizes, int n_in,
                              void* d_out, int out_size, void* d_ws, size_t ws_size,
                              hipStream_t stream) {
  (void)in_sizes; (void)n_in; (void)out_size; (void)ws_size;

  char* ws = (char*)d_ws;
  float* rl    = (float*)(ws + 4096);
  unsigned short* wcv = (unsigned short*)(ws + ((size_t)1 << 20));
  unsigned short* qb  = (unsigned short*)(ws + ((size_t)8  << 20));
  unsigned short* kb  = (unsigned short*)(ws + ((size_t)32 << 20));
  unsigned short* vt  = (unsigned short*)(ws + ((size_t)56 << 20));
  unsigned short* eb  = (unsigned short*)(ws + ((size_t)80 << 20));
  unsigned short* xb  = eb;     // converted x aliases E (x dead before score_k writes E)
  unsigned short* attn = qb;    // Q dead after score_k

  unsigned short* wqb = wcv;
  unsigned short* bqb = wcv + 589824;
  unsigned short* wkb = wcv + 590592;
  unsigned short* bkb = wcv + 1180416;
  unsigned short* wvb = wcv + 1181184;
  unsigned short* bvb = wcv + 1771008;
  unsigned short* wpb = wcv + 1771776;
  unsigned short* bpb = wcv + 2361600;

  const float inv_scale = 0.036084391824351615f;  // 1/sqrt(768)
  dim3 blk(256);

  Cvt9 cv;
  cv.s[0] = d_in[0]; cv.d[0] = xb;  cv.n8[0] = 12582912 / 8;
  cv.s[1] = d_in[1]; cv.d[1] = wqb; cv.n8[1] = 589824 / 8;
  cv.s[2] = d_in[2]; cv.d[2] = bqb; cv.n8[2] = 768 / 8;
  cv.s[3] = d_in[3]; cv.d[3] = wkb; cv.n8[3] = 589824 / 8;
  cv.s[4] = d_in[4]; cv.d[4] = bkb; cv.n8[4] = 768 / 8;
  cv.s[5] = d_in[5]; cv.d[5] = wvb; cv.n8[5] = 589824 / 8;
  cv.s[6] = d_in[6]; cv.d[6] = bvb; cv.n8[6] = 768 / 8;
  cv.s[7] = d_in[7]; cv.d[7] = wpb; cv.n8[7] = 589824 / 8;
  cv.s[8] = d_in[8]; cv.d[8] = bpb; cv.n8[8] = 768 / 8;
  cv.total8 = (12582912 + 4 * (589824 + 768)) / 8;
  convert_inputs<<<(unsigned)((cv.total8 + 255) / 256), blk, 0, stream>>>(cv);

  hipMemsetAsync(rl, 0, 16384 * sizeof(float), stream);

  qkv_k<<<dim3(128, 18, 1), blk, 0, stream>>>(xb, wqb, bqb, wkb, bkb, wvb, bvb, qb, kb, vt);

  score_k<<<dim3(16, 16, 8), blk, 0, stream>>>(qb, kb, eb, rl, inv_scale);

  pv_k<<<dim3(16, 6, 8), blk, 0, stream>>>(eb, vt, rl, attn);

  out_k<<<dim3(128, 6, 1), blk, 0, stream>>>(attn, wpb, bpb, (float*)d_out);
}

// Round 6
// 362.586 us; speedup vs baseline: 1.0296x; 1.0296x over previous
//
#include <hip/hip_runtime.h>
#include <stdint.h>

// MultiHeadAttention  B=8, S=2048, D=768  (fp32 in/out; bf16 MFMA compute)
//
// Pipeline:
//   convert : all 9 fp32 inputs -> bf16 in ws
//   qkv_k   : fused Q/K/V projections (grid 128x18); V stored transposed Vt[b][e][s]
//   score_k : E = exp(min(Q.K^T/sqrt(D),30)) bf16 + fused rowsum atomicAdd -> rl (raw sums)
//   pv_k    : attn = (E @ V) * rcp(rl)
//   out_k   : out = attn@Wp^T + bp  (fp32)
//
// GEMM core: 128x128 tile, BK=64, global_load_lds width=16, 16x16x32 bf16 MFMA.
// *** LDS bank-conflict swizzle (this round's change) ***
// R4 counters showed 7.57e6 SQ_LDS_BANK_CONFLICT: fragment reads at row-stride
// 64B put 8 lanes on one 4-bank window (8-way). Since global_load_lds forces
// LDS slot = thread id, we permute the GLOBAL source instead: 16B-unit (row,q)
// is stored at slot row*4 + ((q + (row>>1)) & 3). Fragment reads then start at
// 8 distinct 4-bank windows per 16-lane phase (2-way only = free, m136).
// All epilogues stage C through LDS (pad 136) and store 16B-vectorized.

typedef __attribute__((ext_vector_type(8))) short short8;
typedef __attribute__((ext_vector_type(4))) float f32x4;

typedef const __attribute__((address_space(1))) void gvoid_t;
typedef __attribute__((address_space(3))) void lvoid_t;

__device__ __forceinline__ float b2f(unsigned short u) {
  union { unsigned int u; float f; } v;
  v.u = ((unsigned int)u) << 16;
  return v.f;
}
__device__ __forceinline__ unsigned short f2b(float f) {
  union { float f; unsigned int u; } v; v.f = f;
  unsigned int u = v.u;
  return (unsigned short)((u + 0x7fffu + ((u >> 16) & 1u)) >> 16);
}

// ---------------- fp32 -> bf16 conversion ----------------
struct Cvt9 {
  const void* s[9];
  unsigned short* d[9];
  long long n8[9];
  long long total8;
};

__global__ __launch_bounds__(256) void convert_inputs(Cvt9 C) {
  long long g = (long long)blockIdx.x * 256 + threadIdx.x;
  if (g >= C.total8) return;
  int s = 0;
  long long off = g;
  while (off >= C.n8[s]) { off -= C.n8[s]; ++s; }
  const float* sf = (const float*)C.s[s] + off * 8;
  unsigned short* dp = C.d[s] + off * 8;
  float4 a = ((const float4*)sf)[0];
  float4 b = ((const float4*)sf)[1];
  uint4 o;
  o.x = (unsigned int)f2b(a.x) | ((unsigned int)f2b(a.y) << 16);
  o.y = (unsigned int)f2b(a.z) | ((unsigned int)f2b(a.w) << 16);
  o.z = (unsigned int)f2b(b.x) | ((unsigned int)f2b(b.y) << 16);
  o.w = (unsigned int)f2b(b.z) | ((unsigned int)f2b(b.w) << 16);
  *(uint4*)dp = o;
}

// ---------------- GEMM core (NT, BK=64, bank-conflict-swizzled LDS) ----------------
// LDS per matrix: [2 chunks][2 rblocks][256 16B-slots]; slot(row,q) = row*4 + ((q+(row>>1))&3)
__device__ __forceinline__ void gemm_core(
    const unsigned short* __restrict__ Ab, const unsigned short* __restrict__ Bb,
    int lda, int ldb, int K, int m0, int n0,
    unsigned short* As, unsigned short* Bs, f32x4 (&acc)[4][4])
{
  const int t    = threadIdx.x;
  const int w    = t >> 6;
  const int lane = t & 63;
  const int lo   = lane & 15;
  const int quad = lane >> 4;
  const int wr   = w >> 1;
  const int wc   = w & 1;
  const int srow  = t >> 2;                              // staging row 0..63
  const int sq    = ((t & 3) - ((t >> 3) & 3)) & 3;      // swizzled source k-slot
  const int skoff = sq * 8;
  const int rq    = ((quad + (lo >> 1)) & 3) * 8;        // swizzled read k-offset (elems)

  for (int k0 = 0; k0 < K; k0 += 64) {
#pragma unroll
    for (int c = 0; c < 2; ++c) {
#pragma unroll
      for (int r = 0; r < 2; ++r) {
        const unsigned short* ga = Ab + (size_t)(m0 + r * 64 + srow) * lda + (k0 + c * 32 + skoff);
        __builtin_amdgcn_global_load_lds((gvoid_t*)ga, (lvoid_t*)(As + c * 4096 + r * 2048 + w * 512), 16, 0, 0);
        const unsigned short* gb = Bb + (size_t)(n0 + r * 64 + srow) * ldb + (k0 + c * 32 + skoff);
        __builtin_amdgcn_global_load_lds((gvoid_t*)gb, (lvoid_t*)(Bs + c * 4096 + r * 2048 + w * 512), 16, 0, 0);
      }
    }
    __syncthreads();

#pragma unroll
    for (int c = 0; c < 2; ++c) {
      short8 af[4], bf[4];
#pragma unroll
      for (int i = 0; i < 4; ++i)
        af[i] = *(const short8*)(As + c * 4096 + wr * 2048 + (i * 16 + lo) * 32 + rq);
#pragma unroll
      for (int j = 0; j < 4; ++j)
        bf[j] = *(const short8*)(Bs + c * 4096 + wc * 2048 + (j * 16 + lo) * 32 + rq);

#pragma unroll
      for (int i = 0; i < 4; ++i)
#pragma unroll
        for (int j = 0; j < 4; ++j)
          acc[i][j] = __builtin_amdgcn_mfma_f32_16x16x32_bf16(af[i], bf[j], acc[i][j], 0, 0, 0);
    }
    __syncthreads();
  }
}

// ---------------- epilogue helpers ----------------
// mode 0: v += bias[ct] ; mode 2: v = exp(min(v*scale,30)) ; mode 3: v *= rcp(rl[row])
__device__ __forceinline__ void tile_to_lds(
    unsigned short* Ls, f32x4 (&acc)[4][4], int mode,
    const unsigned short* bias_n0, const float* rlrow, float scale)
{
  const int t = threadIdx.x;
  const int w = t >> 6, lane = t & 63;
  const int lo = lane & 15, quad = lane >> 4, wr = w >> 1, wc = w & 1;
#pragma unroll
  for (int j = 0; j < 4; ++j) {
    const int ct = wc * 64 + j * 16 + lo;
    const float bv = (mode == 0) ? b2f(bias_n0[ct]) : 0.f;
#pragma unroll
    for (int i = 0; i < 4; ++i) {
      const int rt = wr * 64 + i * 16 + quad * 4;
#pragma unroll
      for (int r = 0; r < 4; ++r) {
        float v = acc[i][j][r];
        if (mode == 0)      v += bv;
        else if (mode == 2) v = __expf(fminf(v * scale, 30.f));
        else                v *= __builtin_amdgcn_rcpf(rlrow[rt + r]);
        Ls[(rt + r) * 136 + ct] = f2b(v);
      }
    }
  }
  __syncthreads();
}

__device__ __forceinline__ void lds_to_global_bf16(
    const unsigned short* Ls, unsigned short* Cg, int ldc)
{
  const int t = threadIdx.x;
  const int cr = t >> 4, cc = (t & 15) * 8;
#pragma unroll
  for (int r0 = 0; r0 < 128; r0 += 16) {
    uint4 v = *(const uint4*)(Ls + (r0 + cr) * 136 + cc);
    *(uint4*)(Cg + (size_t)(r0 + cr) * ldc + cc) = v;
  }
}

// ---------------- qkv: fused projections ----------------
__global__ __launch_bounds__(256, 2) void qkv_k(
    const unsigned short* __restrict__ xb,
    const unsigned short* __restrict__ Wq, const unsigned short* __restrict__ bq,
    const unsigned short* __restrict__ Wk, const unsigned short* __restrict__ bk,
    const unsigned short* __restrict__ Wv, const unsigned short* __restrict__ bv,
    unsigned short* __restrict__ qb, unsigned short* __restrict__ kb,
    unsigned short* __restrict__ vt)
{
  __shared__ unsigned short smem[17408];
  const int sel = blockIdx.y / 6;
  const int n0  = (blockIdx.y % 6) * 128;
  const int m0  = blockIdx.x * 128;

  const unsigned short* W;
  const unsigned short* bi;
  if (sel == 0)      { W = Wq; bi = bq; }
  else if (sel == 1) { W = Wk; bi = bk; }
  else               { W = Wv; bi = bv; }

  f32x4 acc[4][4] = {};
  gemm_core(xb, W, 768, 768, 768, m0, n0, smem, smem + 8192, acc);

  const int t = threadIdx.x;
  const int w = t >> 6, lane = t & 63;
  const int lo = lane & 15, quad = lane >> 4, wr = w >> 1, wc = w & 1;

  if (sel < 2) {
    tile_to_lds(smem, acc, 0, bi + n0, nullptr, 0.f);
    unsigned short* dst = (sel == 0) ? qb : kb;
    lds_to_global_bf16(smem, dst + (size_t)m0 * 768 + n0, 768);
    return;
  }

  // V: transpose epilogue into Vt[b][e][s]  (Ls as [col][row], stride 136)
  unsigned short* Ls = smem;
#pragma unroll
  for (int i = 0; i < 4; ++i) {
    const int rt = wr * 64 + i * 16 + quad * 4;
#pragma unroll
    for (int j = 0; j < 4; ++j) {
      const int ct = wc * 64 + j * 16 + lo;
      const float bvv = b2f(bi[n0 + ct]);
      ushort4 pk;
      pk.x = f2b(acc[i][j][0] + bvv);
      pk.y = f2b(acc[i][j][1] + bvv);
      pk.z = f2b(acc[i][j][2] + bvv);
      pk.w = f2b(acc[i][j][3] + bvv);
      *(ushort4*)(Ls + ct * 136 + rt) = pk;
    }
  }
  __syncthreads();
  const int bb  = m0 >> 11;
  const int sin = m0 & 2047;
  unsigned short* Cb = vt + (size_t)bb * (768 * 2048);
#pragma unroll
  for (int e0 = 0; e0 < 128; e0 += 16) {
    const int et = e0 + (t >> 4);
    const int st = (t & 15) * 8;
    uint4 val = *(const uint4*)(Ls + et * 136 + st);
    *(uint4*)(Cb + (size_t)(n0 + et) * 2048 + (sin + st)) = val;
  }
}

// ---------------- score: E = exp(QK^T/sqrt(D)) + fused rowsum ----------------
__global__ __launch_bounds__(256, 2) void score_k(
    const unsigned short* __restrict__ Q, const unsigned short* __restrict__ Kb,
    unsigned short* __restrict__ E, float* __restrict__ rl, float scale)
{
  __shared__ unsigned short smem[17408];
  const int m0 = blockIdx.x * 128, n0 = blockIdx.y * 128, bz = blockIdx.z;

  f32x4 acc[4][4] = {};
  gemm_core(Q + (size_t)bz * 1572864, Kb + (size_t)bz * 1572864,
            768, 768, 768, m0, n0, smem, smem + 8192, acc);

  tile_to_lds(smem, acc, 2, nullptr, nullptr, scale);
  lds_to_global_bf16(smem, E + (size_t)bz * 4194304 + (size_t)m0 * 2048 + n0, 2048);

  // fused partial rowsum from the staged LDS tile
  const int t = threadIdx.x;
  const int row = t >> 1, half = t & 1;
  const unsigned short* lr = smem + row * 136 + half * 64;
  float s = 0.f;
#pragma unroll
  for (int q8 = 0; q8 < 8; ++q8) {
    uint4 v = *(const uint4*)(lr + q8 * 8);
    unsigned int uu[4] = {v.x, v.y, v.z, v.w};
#pragma unroll
    for (int c = 0; c < 4; ++c)
      s += b2f((unsigned short)(uu[c] & 0xffffu)) + b2f((unsigned short)(uu[c] >> 16));
  }
  s += __shfl_xor(s, 1);
  if (half == 0) atomicAdd(rl + bz * 2048 + m0 + row, s);
}

// ---------------- pv: attn = (E @ V) * rcp(rowsum) ----------------
__global__ __launch_bounds__(256, 2) void pv_k(
    const unsigned short* __restrict__ E, const unsigned short* __restrict__ Vt,
    const float* __restrict__ rl, unsigned short* __restrict__ attn)
{
  __shared__ unsigned short smem[17408];
  const int m0 = blockIdx.x * 128, n0 = blockIdx.y * 128, bz = blockIdx.z;

  f32x4 acc[4][4] = {};
  gemm_core(E + (size_t)bz * 4194304, Vt + (size_t)bz * 1572864,
            2048, 2048, 2048, m0, n0, smem, smem + 8192, acc);

  tile_to_lds(smem, acc, 3, nullptr, rl + bz * 2048 + m0, 0.f);
  lds_to_global_bf16(smem, attn + (size_t)bz * 1572864 + (size_t)m0 * 768 + n0, 768);
}

// ---------------- out: final projection (fp32 output) ----------------
__global__ __launch_bounds__(256, 2) void out_k(
    const unsigned short* __restrict__ attn,
    const unsigned short* __restrict__ Wp, const unsigned short* __restrict__ bp,
    float* __restrict__ Of)
{
  __shared__ unsigned short smem[17408];
  const int m0 = blockIdx.x * 128, n0 = blockIdx.y * 128;

  f32x4 acc[4][4] = {};
  gemm_core(attn, Wp, 768, 768, 768, m0, n0, smem, smem + 8192, acc);

  // fp32 output: two half-tiles (cols 0-63 then 64-127) staged as float through LDS
  const int t = threadIdx.x;
  const int w = t >> 6, lane = t & 63;
  const int lo = lane & 15, quad = lane >> 4, wr = w >> 1, wc = w & 1;
  float* Lf = (float*)smem;     // 128 x 68 floats = 34816 B
#pragma unroll
  for (int h = 0; h < 2; ++h) {
    __syncthreads();
    if (wc == h) {
#pragma unroll
      for (int j = 0; j < 4; ++j) {
        const int cl = j * 16 + lo;                 // 0..63 within half
        const float bvv = b2f(bp[n0 + h * 64 + cl]);
#pragma unroll
        for (int i = 0; i < 4; ++i) {
          const int rt = wr * 64 + i * 16 + quad * 4;
#pragma unroll
          for (int r = 0; r < 4; ++r)
            Lf[(rt + r) * 68 + cl] = acc[i][j][r] + bvv;
        }
      }
    }
    __syncthreads();
    const int cr = t >> 4, cc = (t & 15) * 4;
#pragma unroll
    for (int r0 = 0; r0 < 128; r0 += 16) {
      float4 v = *(const float4*)(Lf + (r0 + cr) * 68 + cc);
      *(float4*)(Of + (size_t)(m0 + r0 + cr) * 768 + n0 + h * 64 + cc) = v;
    }
  }
}

extern "C" void kernel_launch(void* const* d_in, const int* in_sizes, int n_in,
                              void* d_out, int out_size, void* d_ws, size_t ws_size,
                              hipStream_t stream) {
  (void)in_sizes; (void)n_in; (void)out_size; (void)ws_size;

  char* ws = (char*)d_ws;
  float* rl    = (float*)(ws + 4096);
  unsigned short* wcv = (unsigned short*)(ws + ((size_t)1 << 20));
  unsigned short* qb  = (unsigned short*)(ws + ((size_t)8  << 20));
  unsigned short* kb  = (unsigned short*)(ws + ((size_t)32 << 20));
  unsigned short* vt  = (unsigned short*)(ws + ((size_t)56 << 20));
  unsigned short* eb  = (unsigned short*)(ws + ((size_t)80 << 20));
  unsigned short* xb  = eb;     // converted x aliases E (x dead before score_k writes E)
  unsigned short* attn = qb;    // Q dead after score_k

  unsigned short* wqb = wcv;
  unsigned short* bqb = wcv + 589824;
  unsigned short* wkb = wcv + 590592;
  unsigned short* bkb = wcv + 1180416;
  unsigned short* wvb = wcv + 1181184;
  unsigned short* bvb = wcv + 1771008;
  unsigned short* wpb = wcv + 1771776;
  unsigned short* bpb = wcv + 2361600;

  const float inv_scale = 0.036084391824351615f;  // 1/sqrt(768)
  dim3 blk(256);

  Cvt9 cv;
  cv.s[0] = d_in[0]; cv.d[0] = xb;  cv.n8[0] = 12582912 / 8;
  cv.s[1] = d_in[1]; cv.d[1] = wqb; cv.n8[1] = 589824 / 8;
  cv.s[2] = d_in[2]; cv.d[2] = bqb; cv.n8[2] = 768 / 8;
  cv.s[3] = d_in[3]; cv.d[3] = wkb; cv.n8[3] = 589824 / 8;
  cv.s[4] = d_in[4]; cv.d[4] = bkb; cv.n8[4] = 768 / 8;
  cv.s[5] = d_in[5]; cv.d[5] = wvb; cv.n8[5] = 589824 / 8;
  cv.s[6] = d_in[6]; cv.d[6] = bvb; cv.n8[6] = 768 / 8;
  cv.s[7] = d_in[7]; cv.d[7] = wpb; cv.n8[7] = 589824 / 8;
  cv.s[8] = d_in[8]; cv.d[8] = bpb; cv.n8[8] = 768 / 8;
  cv.total8 = (12582912 + 4 * (589824 + 768)) / 8;
  convert_inputs<<<(unsigned)((cv.total8 + 255) / 256), blk, 0, stream>>>(cv);

  hipMemsetAsync(rl, 0, 16384 * sizeof(float), stream);

  qkv_k<<<dim3(128, 18, 1), blk, 0, stream>>>(xb, wqb, bqb, wkb, bkb, wvb, bvb, qb, kb, vt);

  score_k<<<dim3(16, 16, 8), blk, 0, stream>>>(qb, kb, eb, rl, inv_scale);

  pv_k<<<dim3(16, 6, 8), blk, 0, stream>>>(eb, vt, rl, attn);

  out_k<<<dim3(128, 6, 1), blk, 0, stream>>>(attn, wpb, bpb, (float*)d_out);
}